// Round 1
// baseline (213.185 us; speedup 1.0000x reference)
//
#include <hip/hip_runtime.h>

#define B 16
#define E 1024
#define T 1025     // tokens incl. mean token
#define SP 1024    // spatial tokens
#define H 16
#define CH 64

__inline__ __device__ float blockReduceSum(float v, float* sm) {
    int tid = threadIdx.x;
    sm[tid] = v; __syncthreads();
    for (int s = 128; s > 0; s >>= 1) {
        if (tid < s) sm[tid] += sm[tid + s];
        __syncthreads();
    }
    float r = sm[0]; __syncthreads();
    return r;
}

__inline__ __device__ float blockReduceMax(float v, float* sm) {
    int tid = threadIdx.x;
    sm[tid] = v; __syncthreads();
    for (int s = 128; s > 0; s >>= 1) {
        if (tid < s) sm[tid] = fmaxf(sm[tid], sm[tid + s]);
        __syncthreads();
    }
    float r = sm[0]; __syncthreads();
    return r;
}

// K1: per (b,e) row: x0[b,e] = mean_t x[b,e,t] + pos_emb[e,0]
__global__ void k_mean_x0(const float* __restrict__ x, const float* __restrict__ pos,
                          float* __restrict__ x0) {
    int row = blockIdx.x;          // b*E + e
    int e = row & (E - 1);
    const float4* x4 = (const float4*)(x + (size_t)row * SP);
    float4 v = x4[threadIdx.x];
    float s = v.x + v.y + v.z + v.w;
    __shared__ float sm[256];
    float tot = blockReduceSum(s, sm);
    if (threadIdx.x == 0)
        x0[row] = tot * (1.0f / SP) + pos[(size_t)e * T];
}

// K2: q0[b,o] = W_q[o,:]·x0[b,:] + b_q[o]
__global__ void k_q0(const float* __restrict__ wqkv, const float* __restrict__ bqkv,
                     const float* __restrict__ x0, float* __restrict__ q0) {
    int o = blockIdx.x, b = blockIdx.y;
    const float4* w4 = (const float4*)(wqkv + (size_t)o * E);
    const float4* x4 = (const float4*)(x0 + (size_t)b * E);
    float4 w = w4[threadIdx.x], xv = x4[threadIdx.x];
    float s = w.x * xv.x + w.y * xv.y + w.z * xv.z + w.w * xv.w;
    __shared__ float sm[256];
    float tot = blockReduceSum(s, sm);
    if (threadIdx.x == 0) q0[b * E + o] = tot + bqkv[o];
}

// K3: u[b,h,e] = 0.125 * sum_c q0[b,h*64+c] * W_k[h*64+c, e]   (scale^2 folded)
__global__ void k_u(const float* __restrict__ wqkv, const float* __restrict__ q0,
                    float* __restrict__ u) {
    int h = blockIdx.x, b = blockIdx.y;
    __shared__ float qs[CH];
    if (threadIdx.x < CH) qs[threadIdx.x] = q0[b * E + h * CH + threadIdx.x];
    __syncthreads();
    float acc[4] = {0.f, 0.f, 0.f, 0.f};
    for (int c = 0; c < CH; ++c) {
        float qv = qs[c];
        const float* wr = wqkv + (size_t)(E + h * CH + c) * E;
        #pragma unroll
        for (int j = 0; j < 4; ++j)
            acc[j] += qv * wr[j * 256 + threadIdx.x];
    }
    float* ur = u + (size_t)(b * H + h) * E;
    #pragma unroll
    for (int j = 0; j < 4; ++j) ur[j * 256 + threadIdx.x] = 0.125f * acc[j];
}

// K4: sc[b,h,s] += sum_{e in chunk} u[b,h,e]*(x[b,e,s-1] + pos[e,s]),  s = 1..1024
__global__ void k_scores(const float* __restrict__ x, const float* __restrict__ pos,
                         const float* __restrict__ u, float* __restrict__ sc) {
    int ec = blockIdx.x;   // e-chunk 0..3
    int st = blockIdx.y;   // s-tile 0..3
    int b  = blockIdx.z;
    int tid = threadIdx.x;
    int tIdx = st * 256 + tid;   // t index 0..1023; s = tIdx+1
    int e0 = ec * 256;
    __shared__ float us[H][256];
    for (int h = 0; h < H; ++h)
        us[h][tid] = u[(size_t)(b * H + h) * E + e0 + tid];
    __syncthreads();
    float acc[H];
    #pragma unroll
    for (int h = 0; h < H; ++h) acc[h] = 0.f;
    for (int el = 0; el < 256; ++el) {
        int e = e0 + el;
        float xv = x[((size_t)(b * E + e)) * SP + tIdx];
        float pv = pos[(size_t)e * T + tIdx + 1];
        float val = xv + pv;
        #pragma unroll
        for (int h = 0; h < H; ++h) acc[h] += us[h][el] * val;
    }
    #pragma unroll
    for (int h = 0; h < H; ++h)
        atomicAdd(&sc[(size_t)(b * H + h) * T + tIdx + 1], acc[h]);
}

// K5: per (b,h): score0 = u·x0; softmax over 1025 scores -> p
__global__ void k_softmax(const float* __restrict__ u, const float* __restrict__ x0,
                          const float* __restrict__ sc, float* __restrict__ p) {
    int bh = blockIdx.x;
    int b = bh >> 4;
    int tid = threadIdx.x;
    __shared__ float sm[256];
    const float4* u4 = (const float4*)(u + (size_t)bh * E);
    const float4* x4 = (const float4*)(x0 + (size_t)b * E);
    float4 uv = u4[tid], xv = x4[tid];
    float d = uv.x * xv.x + uv.y * xv.y + uv.z * xv.z + uv.w * xv.w;
    float s0 = blockReduceSum(d, sm);
    float vals[5];
    #pragma unroll
    for (int k = 0; k < 5; ++k) {
        int idx = tid + k * 256;
        if (idx <= SP) vals[k] = (idx == 0) ? s0 : sc[(size_t)bh * T + idx];
        else vals[k] = -1e30f;
    }
    float mx = vals[0];
    #pragma unroll
    for (int k = 1; k < 5; ++k) mx = fmaxf(mx, vals[k]);
    mx = blockReduceMax(mx, sm);
    float sum = 0.f;
    #pragma unroll
    for (int k = 0; k < 5; ++k) {
        int idx = tid + k * 256;
        if (idx <= SP) { vals[k] = expf(vals[k] - mx); sum += vals[k]; }
    }
    sum = blockReduceSum(sum, sm);
    float inv = 1.0f / sum;
    #pragma unroll
    for (int k = 0; k < 5; ++k) {
        int idx = tid + k * 256;
        if (idx <= SP) p[(size_t)bh * T + idx] = vals[k] * inv;
    }
}

// K6: y[b,h,e] = p[b,h,0]*x0[b,e] + sum_t p[b,h,t+1]*(x[b,e,t] + pos[e,t+1])
__global__ void __launch_bounds__(256) k_y(const float* __restrict__ x,
                                           const float* __restrict__ pos,
                                           const float* __restrict__ p,
                                           const float* __restrict__ x0,
                                           float* __restrict__ y) {
    int ec = blockIdx.x;  // 0..63, 16 e-rows per block
    int b  = blockIdx.y;
    int tid = threadIdx.x;
    int wave = tid >> 6, lane = tid & 63;
    __shared__ float ps[H][SP];   // exactly 64 KB; p[h][t] = p[b,h,t+1]
    for (int i = 0; i < 64; ++i) {
        int idx = i * 256 + tid;
        int h = idx >> 10, t = idx & 1023;
        ps[h][t] = p[(size_t)(b * H + h) * T + t + 1];
    }
    __syncthreads();
    for (int r = 0; r < 4; ++r) {
        int e = ec * 16 + wave * 4 + r;
        float acc[H];
        #pragma unroll
        for (int h = 0; h < H; ++h) acc[h] = 0.f;
        const float* xr = x + ((size_t)(b * E + e)) * SP;
        const float* pr = pos + (size_t)e * T + 1;
        for (int i = 0; i < 16; ++i) {
            int t = i * 64 + lane;
            float val = xr[t] + pr[t];
            #pragma unroll
            for (int h = 0; h < H; ++h) acc[h] += ps[h][t] * val;
        }
        #pragma unroll
        for (int h = 0; h < H; ++h) {
            float v = acc[h];
            for (int off = 32; off > 0; off >>= 1) v += __shfl_down(v, off, 64);
            acc[h] = v;
        }
        if (lane == 0) {
            float x0v = x0[b * E + e];
            #pragma unroll
            for (int h = 0; h < H; ++h) {
                float p0 = p[(size_t)(b * H + h) * T];
                y[(size_t)(b * H + h) * E + e] = acc[h] + p0 * x0v;
            }
        }
    }
}

// K7: a[b,c] = W_v[c,:]·y[b,h(c),:] + b_v[c]
__global__ void k_a(const float* __restrict__ wqkv, const float* __restrict__ bqkv,
                    const float* __restrict__ y, float* __restrict__ a) {
    int c = blockIdx.x, b = blockIdx.y;
    int h = c >> 6;
    const float4* w4 = (const float4*)(wqkv + (size_t)(2 * E + c) * E);
    const float4* y4 = (const float4*)(y + (size_t)(b * H + h) * E);
    float4 w = w4[threadIdx.x], yv = y4[threadIdx.x];
    float s = w.x * yv.x + w.y * yv.y + w.z * yv.z + w.w * yv.w;
    __shared__ float sm[256];
    float tot = blockReduceSum(s, sm);
    if (threadIdx.x == 0) a[b * E + c] = tot + bqkv[2 * E + c];
}

// K8: out[b,o] = W_c[o,:]·a[b,:] + b_c[o]
__global__ void k_out(const float* __restrict__ wc, const float* __restrict__ bc,
                      const float* __restrict__ a, float* __restrict__ out) {
    int o = blockIdx.x, b = blockIdx.y;
    const float4* w4 = (const float4*)(wc + (size_t)o * E);
    const float4* a4 = (const float4*)(a + (size_t)b * E);
    float4 w = w4[threadIdx.x], av = a4[threadIdx.x];
    float s = w.x * av.x + w.y * av.y + w.z * av.z + w.w * av.w;
    __shared__ float sm[256];
    float tot = blockReduceSum(s, sm);
    if (threadIdx.x == 0) out[b * E + o] = tot + bc[o];
}

extern "C" void kernel_launch(void* const* d_in, const int* in_sizes, int n_in,
                              void* d_out, int out_size, void* d_ws, size_t ws_size,
                              hipStream_t stream) {
    const float* x    = (const float*)d_in[0];
    const float* pos  = (const float*)d_in[1];
    const float* wqkv = (const float*)d_in[2];
    const float* bqkv = (const float*)d_in[3];
    const float* wc   = (const float*)d_in[4];
    const float* bc   = (const float*)d_in[5];
    float* out = (float*)d_out;

    float* ws = (float*)d_ws;
    float* x0 = ws;                    // B*E
    float* q0 = x0 + B * E;            // B*E
    float* u  = q0 + B * E;            // B*H*E
    float* sc = u + (size_t)B * H * E; // B*H*T
    float* p  = sc + (size_t)B * H * T;// B*H*T
    float* y  = p + (size_t)B * H * T; // B*H*E
    float* a  = y + (size_t)B * H * E; // B*E

    hipMemsetAsync(sc, 0, (size_t)B * H * T * sizeof(float), stream);

    k_mean_x0<<<B * E, 256, 0, stream>>>(x, pos, x0);
    k_q0<<<dim3(E, B), 256, 0, stream>>>(wqkv, bqkv, x0, q0);
    k_u<<<dim3(H, B), 256, 0, stream>>>(wqkv, q0, u);
    k_scores<<<dim3(4, 4, B), 256, 0, stream>>>(x, pos, u, sc);
    k_softmax<<<B * H, 256, 0, stream>>>(u, x0, sc, p);
    k_y<<<dim3(64, B), 256, 0, stream>>>(x, pos, p, x0, y);
    k_a<<<dim3(E, B), 256, 0, stream>>>(wqkv, bqkv, y, a);
    k_out<<<dim3(E, B), 256, 0, stream>>>(wc, bc, a, out);
}